// Round 3
// baseline (119.029 us; speedup 1.0000x reference)
//
#include <hip/hip_runtime.h>

// Inv2d: B=4, C=128, H=W=64, G=8 (16 ch/grp), K=7, dil=2, pad=6,
// reduce 128->32, span 32->392.
//
// Round 3 (both kernels were latency-bound: VALU<20%, HBM<8%, occ 17%):
//  - red_gen: block = 64 px x all 32 outs. x[128][64] staged in LDS (32 KB,
//    kills the 8x x re-read), wave-uniform output-octet -> w_reduce via
//    s_load (scalar pipe, free). 256 blocks = 1/CU, per-wave ~3k cyc.
//  - inv_apply: channel-split x2 (grid 1024 = 4 blocks/CU, 16 waves/CU;
//    VGPR ~84 allows it). kv phase duplicated x2 (cheap) for 2x more
//    latency-hiding waves.

#define HW 4096   // 64*64
#define NC 128
#define NR 32
#define NG 8
#define KK 49

__global__ __launch_bounds__(256) void red_gen(
    const float* __restrict__ x, const float* __restrict__ w_reduce,
    const float* __restrict__ b_reduce, float* __restrict__ red) {
  // grid: 256 blocks = b(4) x 64-px chunks(64). Block: 64 px, all 32 outs.
  __shared__ float xs[NC][64];       // 32 KB
  int t = threadIdx.x;
  int blk = blockIdx.x;
  int b = blk >> 6;
  int p0 = (blk & 63) * 64;

  // stage x[128 ch][64 px] -> LDS, float4-coalesced, 8 rounds
  const float* xb = x + b * NC * HW + p0;
  int fx = t & 15;                    // float4 index within 64-px row
  int c0 = t >> 4;                    // 16 ch per round
#pragma unroll
  for (int r = 0; r < 8; ++r) {
    int c = c0 + 16 * r;
    float4 v = *(const float4*)(xb + c * HW + fx * 4);
    *(float4*)(&xs[c][fx * 4]) = v;
  }
  __syncthreads();

  int px = t & 63;
  int quad = __builtin_amdgcn_readfirstlane(t >> 6);  // wave-uniform octet id
  const float* wq = w_reduce + quad * 8 * NC;         // scalar base

  float acc[8];
#pragma unroll
  for (int j = 0; j < 8; ++j) acc[j] = b_reduce[quad * 8 + j];

#pragma unroll 8
  for (int k = 0; k < NC; ++k) {
    float xk = xs[k][px];
#pragma unroll
    for (int j = 0; j < 8; ++j) acc[j] += xk * wq[j * NC + k];
  }

  float* rp = red + (b * NR + quad * 8) * HW + p0 + px;
#pragma unroll
  for (int j = 0; j < 8; ++j) rp[j * HW] = acc[j];
}

__global__ __launch_bounds__(256) void inv_apply(
    const float* __restrict__ x, const float* __restrict__ red,
    const float* __restrict__ w_span, const float* __restrict__ b_span,
    float* __restrict__ out) {
  // grid: 1024 = pchunk(16) x half(2) x g(8) x b(4); thread = 1 px, 8 ch
  int blk = blockIdx.x;
  int pchunk = blk & 15;
  int half = (blk >> 4) & 1;
  int g = (blk >> 5) & 7;
  int b = blk >> 8;
  int p = pchunk * 256 + threadIdx.x;
  int h = p >> 6;
  int w = p & 63;

  // pixel's reduced features (coalesced, saddr-form loads)
  float r[NR];
  const float* rp = red + b * NR * HW + p;
#pragma unroll
  for (int o = 0; o < NR; ++o) r[o] = rp[o * HW];

  // Phase 1: 49 dynamic kernel values + clamped per-lane pixel offsets
  float kv[KK];
  int voff[KK];
#pragma unroll
  for (int t = 0; t < KK; ++t) {
    const int i = t / 7, j = t % 7;
    int hh = h + 2 * i - 6;
    int ww = w + 2 * j - 6;
    bool v = ((unsigned)hh < 64u) && ((unsigned)ww < 64u);
    int q = p + (2 * i - 6) * 64 + (2 * j - 6);
    q = min(max(q, 0), HW - 1);            // in-bounds; kv=0 kills garbage
    voff[t] = q;
    const float* wrow = w_span + (g * KK + t) * NR;  // block-uniform -> s_load
    float s0 = b_span[g * KK + t], s1 = 0.f;
#pragma unroll
    for (int o = 0; o < NR; o += 2) {
      s0 += r[o] * wrow[o];
      s1 += r[o + 1] * wrow[o + 1];
    }
    kv[t] = v ? (s0 + s1) : 0.f;
  }

  // Phase 2: 8 channels, uniform base + 49 independent indexed loads each
  const float* xg = x + (b * NC + g * 16 + half * 8) * HW;
  float acc[8];
#pragma unroll
  for (int c = 0; c < 8; ++c) acc[c] = 0.f;

#pragma unroll
  for (int c = 0; c < 8; ++c) {
    const float* xc = xg + c * HW;         // uniform (SGPR) base per channel
#pragma unroll
    for (int t = 0; t < KK; ++t) acc[c] += xc[voff[t]] * kv[t];
  }

  float* op = out + (b * NC + g * 16 + half * 8) * HW + p;
#pragma unroll
  for (int c = 0; c < 8; ++c) op[c * HW] = acc[c];
}

extern "C" void kernel_launch(void* const* d_in, const int* in_sizes, int n_in,
                              void* d_out, int out_size, void* d_ws, size_t ws_size,
                              hipStream_t stream) {
  const float* x        = (const float*)d_in[0];  // [4,128,64,64]
  const float* w_reduce = (const float*)d_in[1];  // [32,128]
  const float* b_reduce = (const float*)d_in[2];  // [32]
  const float* w_span   = (const float*)d_in[3];  // [392,32]
  const float* b_span   = (const float*)d_in[4];  // [392]
  float* out = (float*)d_out;                     // [4,128,64,64]

  float* red = (float*)d_ws;                      // [4,32,64,64] = 2 MB

  red_gen<<<256, 256, 0, stream>>>(x, w_reduce, b_reduce, red);
  inv_apply<<<1024, 256, 0, stream>>>(x, red, w_span, b_span, out);
}